// Round 22
// baseline (371.929 us; speedup 1.0000x reference)
//
#include <hip/hip_runtime.h>
#include <hip/hip_bf16.h>
#include <hip/hip_fp8.h>
#include <math.h>

// Problem constants
#define BB 4
#define SS 4096
#define DD 1024
#define GG 8
#define NN 64
#define GDIM 128
#define BS (BB*SS)                    // 16384 rows
static const size_t BSD  = (size_t)BS * DD;      // 16,777,216
static const size_t BSGN = (size_t)BS * GG * NN; // 8,388,608

typedef __attribute__((ext_vector_type(8))) short bf16x8;
typedef __attribute__((ext_vector_type(4))) float f32x4;
typedef __attribute__((ext_vector_type(4))) uint u32x4;
typedef unsigned char uchar;

__device__ inline ushort f2b(float x) {
    __hip_bfloat16 h = __float2bfloat16(x);
    return *reinterpret_cast<ushort*>(&h);
}
__device__ inline float b2f(ushort u) {
    union { uint q; float f; } x; x.q = ((uint)u) << 16; return x.f;
}
__device__ inline uchar f2fp8(float x) {
    __hip_fp8_e4m3 h(x);
    return *reinterpret_cast<uchar*>(&h);
}
__device__ inline ushort f2h(float x) {
    _Float16 h = (_Float16)x;
    return *reinterpret_cast<ushort*>(&h);
}
__device__ inline float h2f(ushort u) {
    _Float16 h = *reinterpret_cast<_Float16*>(&u);
    return (float)h;
}

#define GL16(gp, lp) __builtin_amdgcn_global_load_lds( \
    (const __attribute__((address_space(1))) void*)(gp), \
    (__attribute__((address_space(3))) void*)(lp), 16, 0, 0)

// ---------------------------------------------------------------------------
// MFMA GEMM core (m97 structure, r6/r8-proven replay-safe):
// 128x128 tile, 4 waves, BK=32, single LDS buffer, __syncthreads fences.
// A [M][LDA] bf16 row-major (gA pre-offset to tile+lane), B^T [N][LDB].
template<int KD, int LDA, int LDB>
__device__ __forceinline__ void mfma_core(
    const ushort* __restrict__ gA, const ushort* __restrict__ gB,
    ushort* lA, ushort* lB, int wave, int lane, f32x4 (&acc)[4][4])
{
    int r = lane & 15, h = lane >> 4;
    int wm = (wave & 1) * 64, wn = (wave >> 1) * 64;
    ushort* lA0 = lA + wave * 1024;
    ushort* lB0 = lB + wave * 1024;
    for (int k0 = 0; k0 < KD; k0 += 32) {
        __syncthreads();
        GL16(gA + k0,            lA0);
        GL16(gA + k0 + 16*LDA,   lA0 + 512);
        GL16(gB + k0,            lB0);
        GL16(gB + k0 + 16*LDB,   lB0 + 512);
        __syncthreads();
        bf16x8 af[4], bfv[4];
        #pragma unroll
        for (int i = 0; i < 4; i++) af[i]  = *(const bf16x8*)&lA[(wm + i*16 + r)*32 + h*8];
        #pragma unroll
        for (int j = 0; j < 4; j++) bfv[j] = *(const bf16x8*)&lB[(wn + j*16 + r)*32 + h*8];
        #pragma unroll
        for (int i = 0; i < 4; i++)
            #pragma unroll
            for (int j = 0; j < 4; j++)
                acc[i][j] = __builtin_amdgcn_mfma_f32_16x16x32_bf16(af[i], bfv[j], acc[i][j], 0, 0, 0);
    }
}

// ---------------------------------------------------------------------------
// K0: prep.  Wg8 = fp8(Wg*16);  BxT [128][256]; A3 [128][256]; WoP [1024][2048];
// spl = softplus(logA); ctab/stab = cos/sin(theta) expanded to 1024.
__global__ __launch_bounds__(256) void k_prep(
    const float* __restrict__ Wg, const float* __restrict__ BWr, const float* __restrict__ BWi,
    const float* __restrict__ CWr, const float* __restrict__ CWi,
    const float* __restrict__ Wor, const float* __restrict__ Woi,
    const float* __restrict__ logA, const float* __restrict__ theta,
    uchar* __restrict__ Wg8, ushort* __restrict__ BxT, ushort* __restrict__ A3,
    ushort* __restrict__ WoP, float* __restrict__ spl,
    float* __restrict__ ctab, float* __restrict__ stab)
{
    const int S1 = 1048576;           // Wg8
    const int S2 = S1 + 32768;        // BxT
    const int S3 = S2 + 32768;        // A3
    const int S4 = S3 + 2097152;      // WoP
    const int S5 = S4 + 512;          // spl
    const int S6 = S5 + 1024;         // ctab
    const int S7 = S6 + 1024;         // stab
    for (int idx = blockIdx.x * 256 + threadIdx.x; idx < S7; idx += gridDim.x * 256) {
        if (idx < S1) {
            Wg8[idx] = f2fp8(Wg[idx] * 16.0f);   // pow-2 pre-scale, undone in epilogue
        } else if (idx < S2) {
            int j = idx - S1, n = j >> 8, kk = j & 255;
            float v;
            if (n < 64) v = (kk < 128) ? BWr[n*128 + kk] : -BWi[n*128 + (kk-128)];
            else { int n2 = n - 64; v = (kk < 128) ? BWi[n2*128 + kk] : BWr[n2*128 + (kk-128)]; }
            BxT[j] = f2b(v);
        } else if (idx < S3) {
            int j = idx - S2, m = j >> 8, kk = j & 255;
            float v;
            if (m < 64) v = (kk < 128) ? CWr[kk*64 + m] : -CWi[(kk-128)*64 + m];
            else { int n2 = m - 64; v = (kk < 128) ? CWi[kk*64 + n2] : CWr[(kk-128)*64 + n2]; }
            A3[j] = f2b(v);
        } else if (idx < S4) {
            int j = idx - S3, e = j >> 11, c = j & 2047;
            int g = c >> 8, kk = c & 255;
            float v = (kk < 128) ? Wor[(size_t)e*1024 + g*128 + kk]
                                 : Woi[(size_t)e*1024 + g*128 + (kk-128)];
            WoP[j] = f2b(v);
        } else if (idx < S5) {
            int j = idx - S4;
            spl[j] = log1pf(expf(logA[j]));
        } else if (idx < S6) {
            int j = idx - S5;
            ctab[j] = cosf(theta[j >> 3]);
        } else {
            int j = idx - S6;
            stab[j] = sinf(theta[j >> 3]);
        }
    }
}

// ---------------------------------------------------------------------------
// K0b: P = C-combined-with-Wo.  Per g: [Pr;Pi](128x1024) = A3(128x256) @ WoP_g^T.
// Emits fp8(P*16) panels [1024 e][512] (pow-2 pre-scale keeps ~0.03-magnitude
// entries out of e4m3 subnormals; undone exactly by x0.0625 in out epilogue).
__global__ __launch_bounds__(256) void k_pgemm(
    const ushort* __restrict__ A3, const ushort* __restrict__ WoP,
    uchar* __restrict__ Ppr, uchar* __restrict__ Ppi)
{
    __shared__ ushort lA[4096], lB[4096];
    int g = blockIdx.z;
    int bn = blockIdx.x * 128;
    int tid = threadIdx.x, wave = tid >> 6, lane = tid & 63;
    int row0 = wave*32 + (lane >> 2), col0 = (lane & 3) * 8;
    int r = lane & 15, h = lane >> 4;
    int wm = (wave & 1) * 64, wn = (wave >> 1) * 64;
    f32x4 acc[4][4] = {};
    mfma_core<256, 256, 2048>(A3 + (size_t)row0*256 + col0,
                              WoP + (size_t)(bn + row0)*2048 + g*256 + col0,
                              lA, lB, wave, lane, acc);
    #pragma unroll
    for (int i = 0; i < 4; i++) {
        int mb = wm + i*16 + h*4;
        #pragma unroll
        for (int j = 0; j < 4; j++) {
            int e = bn + wn + j*16 + r;
            #pragma unroll
            for (int t2 = 0; t2 < 4; t2++) {
                int m = mb + t2;
                float v = acc[i][j][t2] * 16.0f;
                if (m < 64) {
                    Ppr[(size_t)e*512 + g*64 + m] = f2fp8(v);
                } else {
                    Ppi[(size_t)e*512 + g*64 + (m - 64)] = f2fp8(v);
                }
            }
        }
    }
}

// ---------------------------------------------------------------------------
// K1: complex RMSNorm stats: mag (fp8 e4m3) + inv (f32 per row).
__global__ __launch_bounds__(256) void k_norm(
    const float* __restrict__ xr_in, const float* __restrict__ xi_in,
    const float* __restrict__ norm_w,
    uchar* __restrict__ mag_o, float* __restrict__ inv_o)
{
    int row = blockIdx.x;
    int tid = threadIdx.x;
    size_t base = (size_t)row * DD;
    float4 vr = ((const float4*)(xr_in + base))[tid];
    float4 vi = ((const float4*)(xi_in + base))[tid];
    float ss = vr.x*vr.x + vr.y*vr.y + vr.z*vr.z + vr.w*vr.w
             + vi.x*vi.x + vi.y*vi.y + vi.z*vi.z + vi.w*vi.w;
    #pragma unroll
    for (int off = 32; off >= 1; off >>= 1) ss += __shfl_down(ss, off);
    __shared__ float ws4[4];
    if ((tid & 63) == 0) ws4[tid >> 6] = ss;
    __syncthreads();
    float tot = ws4[0] + ws4[1] + ws4[2] + ws4[3];
    float inv = rsqrtf(tot * (1.0f / DD) + 1e-6f);
    float4 w = ((const float4*)norm_w)[tid];
    vr.x *= inv * w.x; vr.y *= inv * w.y; vr.z *= inv * w.z; vr.w *= inv * w.w;
    vi.x *= inv * w.x; vi.y *= inv * w.y; vi.z *= inv * w.z; vi.w *= inv * w.w;
    uchar4 mb;
    mb.x = f2fp8(sqrtf(vr.x*vr.x + vi.x*vi.x + 1e-8f));
    mb.y = f2fp8(sqrtf(vr.y*vr.y + vi.y*vi.y + 1e-8f));
    mb.z = f2fp8(sqrtf(vr.z*vr.z + vi.z*vi.z + 1e-8f));
    mb.w = f2fp8(sqrtf(vr.w*vr.w + vi.w*vi.w + 1e-8f));
    ((uchar4*)(mag_o + base))[tid] = mb;
    if (tid == 0) inv_o[row] = inv;
}

// ---------------------------------------------------------------------------
// K2: gate = sigmoid((mag8 @ Wg8^T)/16 + bg), bf16 out.  WIDE-E fp8 variant
// (r19-proven).  Grid 512 = 8 XCD x 64 chunk (bijective).
__global__ __launch_bounds__(512) void k_gate_fp8(
    const uchar* __restrict__ A8, const uchar* __restrict__ B8,
    const float* __restrict__ bg, ushort* __restrict__ gate)
{
    __shared__ uchar lA[4096], lB[8192];
    int flat = blockIdx.y * 8 + blockIdx.x;          // 0..511
    int nid  = (flat & 7) * 64 + (flat >> 3);        // chunk per XCD
    int bm = (nid >> 2) * 128, bn = (nid & 3) * 256;
    int tid = threadIdx.x, wave = tid >> 6, lane = tid & 63;
    int r = lane & 15, h = lane >> 4;
    int wr = wave >> 2, wc = wave & 3;
    int srow = (lane >> 1);
    int scol = (lane & 1) * 16;
    const uchar* gA = A8 + (size_t)(bm + (wave & 3)*32 + srow)*1024 + scol;       // waves 0-3
    const uchar* gB = B8 + (size_t)(bn + (wave & 3)*64 + srow)*1024 + scol;       // waves 4-7
    uchar* dA = lA + (wave & 3)*1024;
    uchar* dB = lB + (wave & 3)*2048;
    f32x4 acc[4][4] = {};
    for (int k0 = 0; k0 < 1024; k0 += 32) {
        __syncthreads();
        if (wave < 4) {
            GL16(gA + k0, dA);
        } else {
            GL16(gB + k0,            dB);
            GL16(gB + 32*1024 + k0,  dB + 1024);
        }
        __syncthreads();
        long af[4], bfv[4];
        #pragma unroll
        for (int i = 0; i < 4; i++) af[i]  = *(const long*)&lA[(wr*64 + i*16 + r)*32 + h*8];
        #pragma unroll
        for (int j = 0; j < 4; j++) bfv[j] = *(const long*)&lB[(wc*64 + j*16 + r)*32 + h*8];
        #pragma unroll
        for (int i = 0; i < 4; i++)
            #pragma unroll
            for (int j = 0; j < 4; j++)
                acc[i][j] = __builtin_amdgcn_mfma_f32_16x16x32_fp8_fp8(af[i], bfv[j], acc[i][j], 0, 0, 0);
    }
    #pragma unroll
    for (int i = 0; i < 4; i++) {
        int mb = bm + wr*64 + i*16 + h*4;
        #pragma unroll
        for (int j = 0; j < 4; j++) {
            int n = bn + wc*64 + j*16 + r;
            float bias = bg[n];
            #pragma unroll
            for (int t2 = 0; t2 < 4; t2++) {
                float v = acc[i][j][t2] * 0.0625f + bias;   // undo Wg*16
                gate[(size_t)(mb + t2)*DD + n] = f2b(1.0f / (1.0f + __expf(-v)));
            }
        }
    }
}

// ---------------------------------------------------------------------------
// K3: fused rotate + depthwise conv (K=4) + activation + xcat(bf16) + dt.
__global__ __launch_bounds__(256) void k_rotconv(
    const float* __restrict__ xr_raw, const float* __restrict__ xi_raw,
    const float* __restrict__ inv_, const float* __restrict__ norm_w,
    const ushort* __restrict__ gate,
    const float* __restrict__ ctab, const float* __restrict__ stab,
    const float* __restrict__ cw, const float* __restrict__ cb,
    const float* __restrict__ act_thr,
    const float* __restrict__ dtW, const float* __restrict__ dtb,
    ushort* __restrict__ xcat, float* __restrict__ dtm_o, float* __restrict__ dtp_o)
{
    const int CH = 16;
    int row0 = blockIdx.x * CH;
    int s0 = row0 & (SS - 1);
    int t = threadIdx.x, d0 = t * 4;
    int g = d0 >> 7, dd = d0 & 127;
    float4 w4  = *(const float4*)&norm_w[d0];
    float4 ct4 = *(const float4*)&ctab[d0];
    float4 st4 = *(const float4*)&stab[d0];
    float cwv[4][16];
    float cb0[4], cb1[4];
    #pragma unroll
    for (int j = 0; j < 4; j++) {
        #pragma unroll
        for (int q = 0; q < 4; q++)
            *(float4*)&cwv[j][q*4] = *(const float4*)&cw[(size_t)(2*(d0+j))*8 + q*4];
        cb0[j] = cb[2*(d0+j)];
        cb1[j] = cb[2*(d0+j) + 1];
    }
    float4 dtw0a = *(const float4*)&dtW[dd];
    float4 dtw0b = *(const float4*)&dtW[128 + dd];
    float4 dtw1a = *(const float4*)&dtW[256 + dd];
    float4 dtw1b = *(const float4*)&dtW[384 + dd];
    float ea  = __expf(act_thr[0]);
    float db0 = dtb[0], db1 = dtb[1];

    float p1r[4] = {}, p1i[4] = {}, p2r[4] = {}, p2i[4] = {}, p3r[4] = {}, p3i[4] = {};
    auto rotrow = [&](int rr, float (&orr)[4], float (&ori)[4]) {
        float4 a  = *(const float4*)&xr_raw[(size_t)rr*DD + d0];
        float4 bq = *(const float4*)&xi_raw[(size_t)rr*DD + d0];
        ushort4 gq = *(const ushort4*)&gate[(size_t)rr*DD + d0];
        float iv = inv_[rr];
        #pragma unroll
        for (int j = 0; j < 4; j++) {
            float ar = ((const float*)&a)[j]  * iv * ((const float*)&w4)[j];
            float ai = ((const float*)&bq)[j] * iv * ((const float*)&w4)[j];
            float c = ((const float*)&ct4)[j], s = ((const float*)&st4)[j];
            float gg = b2f(((const ushort*)&gq)[j]);
            orr[j] = gg * (ar*c - ai*s);
            ori[j] = gg * (ar*s + ai*c);
        }
    };
    if (s0 >= 1) rotrow(row0 - 1, p1r, p1i);
    if (s0 >= 2) rotrow(row0 - 2, p2r, p2i);
    if (s0 >= 3) rotrow(row0 - 3, p3r, p3i);

    for (int sl = 0; sl < CH; sl++) {
        int row = row0 + sl;
        float rr0[4], ri0[4];
        rotrow(row, rr0, ri0);
        float p0 = 0.f, p1 = 0.f;
        ushort4 ur, ui;
        #pragma unroll
        for (int j = 0; j < 4; j++) {
            float cr = cb0[j]
                + p3r[j]*cwv[j][0]  + p2r[j]*cwv[j][1]  + p1r[j]*cwv[j][2]  + rr0[j]*cwv[j][3]
                + p3i[j]*cwv[j][4]  + p2i[j]*cwv[j][5]  + p1i[j]*cwv[j][6]  + ri0[j]*cwv[j][7];
            float ci = cb1[j]
                + p3r[j]*cwv[j][8]  + p2r[j]*cwv[j][9]  + p1r[j]*cwv[j][10] + rr0[j]*cwv[j][11]
                + p3i[j]*cwv[j][12] + p2i[j]*cwv[j][13] + p1i[j]*cwv[j][14] + ri0[j]*cwv[j][15];
            float act = 1.0f - __expf(-(cr*cr + ci*ci) * ea);
            cr *= act; ci *= act;
            ((ushort*)&ur)[j] = f2b(cr);
            ((ushort*)&ui)[j] = f2b(ci);
            p0 += cr * ((const float*)&dtw0a)[j] + ci * ((const float*)&dtw0b)[j];
            p1 += cr * ((const float*)&dtw1a)[j] + ci * ((const float*)&dtw1b)[j];
        }
        *(ushort4*)&xcat[(size_t)row*2048 + g*256 + dd]       = ur;
        *(ushort4*)&xcat[(size_t)row*2048 + g*256 + 128 + dd] = ui;
        #pragma unroll
        for (int off = 16; off >= 1; off >>= 1) {
            p0 += __shfl_down(p0, off, 32);
            p1 += __shfl_down(p1, off, 32);
        }
        if ((t & 31) == 0) {
            dtm_o[(size_t)row*8 + g] = fminf(fmaxf(__expf(p0 + db0), 1e-4f), 2.0f);
            dtp_o[(size_t)row*8 + g] = fminf(fmaxf(__expf(p1 + db1), 1e-4f), 2.0f);
        }
        #pragma unroll
        for (int j = 0; j < 4; j++) {
            p3r[j] = p2r[j]; p3i[j] = p2i[j];
            p2r[j] = p1r[j]; p2i[j] = p1i[j];
            p1r[j] = rr0[j]; p1i[j] = ri0[j];
        }
    }
}

// ---------------------------------------------------------------------------
// K5: bx = xcat_g @ BxT^T, scaled by dtm; f16 outputs (r19-proven).
__global__ __launch_bounds__(256) void k_bx_mfma(
    const ushort* __restrict__ xcat, const ushort* __restrict__ BxT,
    const float* __restrict__ dtm_,
    ushort* __restrict__ br, ushort* __restrict__ bi)
{
    __shared__ ushort lA[4096], lB[4096];
    int g = blockIdx.z;
    int bm = blockIdx.y * 128;
    int tid = threadIdx.x, wave = tid >> 6, lane = tid & 63;
    int row0 = wave*32 + (lane >> 2), col0 = (lane & 3) * 8;
    int r = lane & 15, h = lane >> 4;
    int wm = (wave & 1) * 64, wn = (wave >> 1) * 64;
    f32x4 acc[4][4] = {};
    mfma_core<256, 2048, 256>(xcat + (size_t)(bm + row0)*2048 + g*256 + col0,
                              BxT + (size_t)row0*256 + col0,
                              lA, lB, wave, lane, acc);
    #pragma unroll
    for (int i = 0; i < 4; i++) {
        int mb = bm + wm + i*16 + h*4;
        #pragma unroll
        for (int j = 0; j < 4; j++) {
            int n = wn + j*16 + r;
            #pragma unroll
            for (int t2 = 0; t2 < 4; t2++) {
                int m = mb + t2;
                float v = acc[i][j][t2] * dtm_[(size_t)m*8 + g];
                if (n < 64) br[(size_t)m*512 + g*64 + n]      = f2h(v);
                else        bi[(size_t)m*512 + g*64 + n - 64] = f2h(v);
            }
        }
    }
}

// ---------------------------------------------------------------------------
// K6: chunked scan, chunk = 64 steps (renorm fires after chunks with c%4==3).
__global__ __launch_bounds__(256) void k_scan1(
    const ushort* __restrict__ br, const ushort* __restrict__ bi,
    const float* __restrict__ dtm_, const float* __restrict__ dtp_,
    const float* __restrict__ spl_t, const float* __restrict__ aph,
    float* __restrict__ Sar, float* __restrict__ Sai,
    float* __restrict__ Sbr, float* __restrict__ Sbi)
{
    int blk = blockIdx.x;                  // 512 = b(4) * c(64) * half(2)
    int half = blk & 1, c = (blk >> 1) & 63, b = blk >> 7;
    int t = half*256 + threadIdx.x;
    int g = t >> 6;
    float spl = spl_t[t], ap = aph[t];
    int row0 = b*SS + c*64;
    size_t idx = (size_t)row0 * 512 + t;
    const float* dtmp = dtm_ + (size_t)row0*8 + g;
    const float* dtpp = dtp_ + (size_t)row0*8 + g;
    float Ar = 1.f, Ai = 0.f, Br = 0.f, Bi = 0.f;
    for (int s0 = 0; s0 < 64; s0 += 4) {
        float vm[4], vp[4], wr[4], wi[4];
        #pragma unroll
        for (int u = 0; u < 4; u++) {
            vm[u] = dtmp[(s0+u)*8]; vp[u] = dtpp[(s0+u)*8];
            wr[u] = h2f(br[idx + (size_t)(s0+u)*512]);
            wi[u] = h2f(bi[idx + (size_t)(s0+u)*512]);
        }
        #pragma unroll
        for (int u = 0; u < 4; u++) {
            float am = __expf(-vm[u]*spl);
            float sa, ca; __sincosf(vp[u]*ap, &sa, &ca);
            float arv = am*ca, aiv = am*sa;
            float nBr = arv*Br - aiv*Bi + wr[u];
            float nBi = arv*Bi + aiv*Br + wi[u];
            float nAr = arv*Ar - aiv*Ai;
            float nAi = arv*Ai + aiv*Ar;
            Br = nBr; Bi = nBi; Ar = nAr; Ai = nAi;
        }
    }
    size_t o = ((size_t)(b*64 + c))*512 + t;
    Sar[o] = Ar; Sai[o] = Ai; Sbr[o] = Br; Sbi[o] = Bi;
}

__global__ __launch_bounds__(256) void k_scan2(
    const float* __restrict__ Sar, const float* __restrict__ Sai,
    const float* __restrict__ Sbr, const float* __restrict__ Sbi,
    float* __restrict__ hinr, float* __restrict__ hini)
{
    int blk = blockIdx.x;                  // 8 = b(4) * half(2)
    int half = blk & 1, b = blk >> 1;
    int t = half*256 + threadIdx.x;
    float hr = 0.f, hi = 0.f;
    for (int c = 0; c < 64; c++) {
        size_t o = ((size_t)(b*64 + c))*512 + t;
        hinr[o] = hr; hini[o] = hi;
        float nr = Sar[o]*hr - Sai[o]*hi + Sbr[o];
        float ni = Sar[o]*hi + Sai[o]*hr + Sbi[o];
        if ((c & 3) == 3) {
            float hn = sqrtf(nr*nr + ni*ni + 1e-8f);
            float sc = fminf(hn, 100.0f) / hn;
            nr *= sc; ni *= sc;
        }
        hr = nr; hi = ni;
    }
}

// scan3: recompute states; write H as fp8 A-matrix [row][1024] = [Hr|Hi]
// (|H| <= ~100 << 448 e4m3 max; halves scan3 write traffic and out staging).
__global__ __launch_bounds__(256) void k_scan3(
    const ushort* __restrict__ br, const ushort* __restrict__ bi,
    const float* __restrict__ dtm_, const float* __restrict__ dtp_,
    const float* __restrict__ spl_t, const float* __restrict__ aph,
    const float* __restrict__ hinr, const float* __restrict__ hini,
    uchar* __restrict__ H8)
{
    int blk = blockIdx.x;
    int half = blk & 1, c = (blk >> 1) & 63, b = blk >> 7;
    int t = half*256 + threadIdx.x;
    int g = t >> 6;
    float spl = spl_t[t], ap = aph[t];
    int row0 = b*SS + c*64;
    size_t idx = (size_t)row0 * 512 + t;
    const float* dtmp = dtm_ + (size_t)row0*8 + g;
    const float* dtpp = dtp_ + (size_t)row0*8 + g;
    size_t o = ((size_t)(b*64 + c))*512 + t;
    float hr = hinr[o], hi = hini[o];
    bool rch = ((c & 3) == 3);
    for (int s0 = 0; s0 < 64; s0 += 4) {
        float vm[4], vp[4], wr[4], wi[4];
        #pragma unroll
        for (int u = 0; u < 4; u++) {
            vm[u] = dtmp[(s0+u)*8]; vp[u] = dtpp[(s0+u)*8];
            wr[u] = h2f(br[idx + (size_t)(s0+u)*512]);
            wi[u] = h2f(bi[idx + (size_t)(s0+u)*512]);
        }
        #pragma unroll
        for (int u = 0; u < 4; u++) {
            float am = __expf(-vm[u]*spl);
            float sa, ca; __sincosf(vp[u]*ap, &sa, &ca);
            float arv = am*ca, aiv = am*sa;
            float nr = arv*hr - aiv*hi + wr[u];
            float ni = arv*hi + aiv*hr + wi[u];
            if (rch && (s0 + u == 63)) {
                float hn = sqrtf(nr*nr + ni*ni + 1e-8f);
                float sc = fminf(hn, 100.0f) / hn;
                nr *= sc; ni *= sc;
            }
            size_t rb = (size_t)(row0 + s0 + u) * 1024;
            H8[rb + t]       = f2fp8(nr);
            H8[rb + 512 + t] = f2fp8(ni);
            hr = nr; hi = ni;
        }
    }
}

// ---------------------------------------------------------------------------
// K7: complex-fused out GEMM, WIDE-E FP8 variant.  Per block 128 m x 256 e,
// both real+imag; fp8 operands: per K-step stages {Hr 4K, Hi 4K, Pr 8K,
// Pi 8K} = 24KB for 512 fp8-MFMA (21.3 MFMA/KB; staged total 194 MB, half
// of r19's 388 — the thrice-validated per-staged-byte lever).  Same
// single-buffer __syncthreads skeleton (race-free).  P stored as fp8(P*16);
// epilogue x0.0625 undoes it.  Pi negation = sign-bit XOR (exact in e4m3).
// Staging: lane l -> row l>>1, byte (l&1)*16 (linear dest == row-major since
// (l>>1)*32+(l&1)*16 == l*16); waves 0-3: {Hr 1 GL16, Pr 2 GL16}; waves 4-7:
// {Hi, Pi}.  Fragment reads = r15-proven fp8 16x16x32 layout (8B/lane).
// Grid 512 = 8 XCD x 64 chunk (bijective).
__global__ __launch_bounds__(512) void k_out_cplx(
    const uchar* __restrict__ H8,      // [16384][1024]: Hr fp8 (512) | Hi fp8 (512)
    const uchar* __restrict__ Ppr,     // [1024 e][512] fp8 (P*16)
    const uchar* __restrict__ Ppi,     // [1024 e][512] fp8 (P*16)
    const float* __restrict__ ssm,
    const float* __restrict__ xr0, const float* __restrict__ xi0,
    const float* __restrict__ res_scale, float* __restrict__ out)
{
    __shared__ uchar lHr[4096], lHi[4096], lPr[8192], lPi[8192];   // 24KB
    int flat = blockIdx.y * 8 + blockIdx.x;          // 0..511
    int nid  = (flat & 7) * 64 + (flat >> 3);        // chunk per XCD
    int bm = (nid >> 2) * 128, be = (nid & 3) * 256;
    int tid = threadIdx.x, wave = tid >> 6, lane = tid & 63;
    int r = lane & 15, h = lane >> 4;
    int wr = wave >> 2, wc = wave & 3;
    int w4 = wave & 3;
    int lrow = lane >> 1;                            // 0..31
    int lcol = (lane & 1) * 16;                      // bytes
    const uchar* gH = H8 + (size_t)(bm + w4*32 + lrow)*1024 + (wave < 4 ? 0 : 512) + lcol;
    const uchar* gP = (wave < 4 ? Ppr : Ppi) + (size_t)(be + w4*64 + lrow)*512 + lcol;
    uchar* dH = (wave < 4 ? lHr : lHi) + w4*1024;
    uchar* dP = (wave < 4 ? lPr : lPi) + w4*2048;
    f32x4 accr[4][4] = {};
    f32x4 acci[4][4] = {};
    for (int k0 = 0; k0 < 512; k0 += 32) {
        __syncthreads();
        GL16(gH + k0,          dH);
        GL16(gP + k0,          dP);
        GL16(gP + 32*512 + k0, dP + 1024);
        __syncthreads();
        long hrf[4], hif[4], prf[4], pif[4], npif[4];
        #pragma unroll
        for (int i = 0; i < 4; i++) {
            int ro = (wr*64 + i*16 + r)*32 + h*8;
            hrf[i] = *(const long*)&lHr[ro];
            hif[i] = *(const long*)&lHi[ro];
        }
        #pragma unroll
        for (int j = 0; j < 4; j++) {
            int ro = (wc*64 + j*16 + r)*32 + h*8;
            prf[j] = *(const long*)&lPr[ro];
            pif[j] = *(const long*)&lPi[ro];
            npif[j] = pif[j] ^ (long)0x8080808080808080ULL;
        }
        #pragma unroll
        for (int i = 0; i < 4; i++)
            #pragma unroll
            for (int j = 0; j < 4; j++) {
                accr[i][j] = __builtin_amdgcn_mfma_f32_16x16x32_fp8_fp8(hrf[i], prf[j],  accr[i][j], 0, 0, 0);
                accr[i][j] = __builtin_amdgcn_mfma_f32_16x16x32_fp8_fp8(hif[i], npif[j], accr[i][j], 0, 0, 0);
                acci[i][j] = __builtin_amdgcn_mfma_f32_16x16x32_fp8_fp8(hrf[i], pif[j],  acci[i][j], 0, 0, 0);
                acci[i][j] = __builtin_amdgcn_mfma_f32_16x16x32_fp8_fp8(hif[i], prf[j],  acci[i][j], 0, 0, 0);
            }
    }
    float rs = res_scale[0] * 0.0625f;               // undo P*16
    #pragma unroll
    for (int i = 0; i < 4; i++) {
        int mb = bm + wr*64 + i*16 + h*4;
        #pragma unroll
        for (int j = 0; j < 4; j++) {
            int e = be + wc*64 + j*16 + r;
            float sc = ssm[e] * rs;
            #pragma unroll
            for (int t2 = 0; t2 < 4; t2++) {
                size_t p = (size_t)(mb + t2)*DD + e;
                float2 v;
                v.x = xr0[p] + accr[i][j][t2]*sc;
                v.y = xi0[p] + acci[i][j][t2]*sc;
                *(float2*)&out[2*p] = v;
            }
        }
    }
}

// ---------------------------------------------------------------------------
extern "C" void kernel_launch(void* const* d_in, const int* in_sizes, int n_in,
                              void* d_out, int out_size, void* d_ws, size_t ws_size,
                              hipStream_t stream) {
    const float* x_r      = (const float*)d_in[0];
    const float* x_i      = (const float*)d_in[1];
    const float* norm_w   = (const float*)d_in[2];
    const float* sg_theta = (const float*)d_in[3];
    const float* sg_Wg    = (const float*)d_in[4];
    const float* sg_bg    = (const float*)d_in[5];
    const float* conv_w   = (const float*)d_in[6];
    const float* conv_b   = (const float*)d_in[7];
    const float* log_A    = (const float*)d_in[8];
    const float* A_phase  = (const float*)d_in[9];
    const float* B_Wr     = (const float*)d_in[10];
    const float* B_Wi     = (const float*)d_in[11];
    const float* C_Wr     = (const float*)d_in[12];
    const float* C_Wi     = (const float*)d_in[13];
    const float* dt_W     = (const float*)d_in[14];
    const float* dt_b     = (const float*)d_in[15];
    const float* out_Wr   = (const float*)d_in[16];
    const float* out_Wi   = (const float*)d_in[17];
    const float* act_thr  = (const float*)d_in[18];
    const float* ssm_s    = (const float*)d_in[19];
    const float* res_s    = (const float*)d_in[20];
    float* out = (float*)d_out;
    float* ws  = (float*)d_ws;

    ushort* gate  = (ushort*)ws;                         // BS*1024 bf16 (in BSD f32 slots)
    ushort* xcat  = (ushort*)(ws + BSD);                 // BS*2048 bf16 (BSD f32 slots)
    uchar*  mag8  = (uchar*)(ws + 2*BSD);                // BS*1024 fp8 (16MB, in BSGN slot)
    ushort* br    = (ushort*)(ws + 2*BSD + BSGN);        // BSGN f16 (in BSGN f32 slots)
    ushort* bi    = (ushort*)(ws + 2*BSD + 2*BSGN);      // BSGN f16
    uchar*  H8    = (uchar*)(ws + 2*BSD + 3*BSGN);       // BS*1024 fp8 (16MB, BSGN slot)
    float*  sm    = ws + 2*BSD + 4*BSGN;
    float*  dtm   = sm;
    float*  dtp   = sm + 131072;
    float*  Sar   = sm + 2*131072;
    float*  Sai   = sm + 3*131072;
    float*  Sbr   = sm + 4*131072;
    float*  Sbi   = sm + 5*131072;
    float*  hinr  = sm + 6*131072;
    float*  hini  = sm + 7*131072;
    float*  inv   = sm + 8*131072;                       // 16384
    float*  spl   = inv + 16384;                         // 512
    float*  ctab  = spl + 512;                           // 1024
    float*  stab  = ctab + 1024;                         // 1024
    uchar*  Wg8   = (uchar*)(stab + 1024);               // 1048576 bytes (262144 f32 slots)
    ushort* BxT   = (ushort*)(stab + 1024 + 262144);     // 32768 ushorts
    ushort* A3    = BxT + 32768;                         // 32768
    ushort* WoP   = A3 + 32768;                          // 2097152
    uchar*  Ppr   = (uchar*)(WoP + 2097152);             // 524288 bytes
    uchar*  Ppi   = Ppr + 524288;                        // 524288 bytes

    k_prep<<<2048, 256, 0, stream>>>(sg_Wg, B_Wr, B_Wi, C_Wr, C_Wi, out_Wr, out_Wi,
                                     log_A, sg_theta, Wg8, BxT, A3, WoP, spl, ctab, stab);
    k_pgemm<<<dim3(8, 1, 8), 256, 0, stream>>>(A3, WoP, Ppr, Ppi);
    k_norm<<<BS, 256, 0, stream>>>(x_r, x_i, norm_w, mag8, inv);
    k_gate_fp8<<<dim3(8, 64), 512, 0, stream>>>(mag8, Wg8, sg_bg, gate);
    k_rotconv<<<BS/16, 256, 0, stream>>>(x_r, x_i, inv, norm_w, gate, ctab, stab,
                                         conv_w, conv_b, act_thr, dt_W, dt_b,
                                         xcat, dtm, dtp);
    k_bx_mfma<<<dim3(1, 128, 8), 256, 0, stream>>>(xcat, BxT, dtm, br, bi);
    k_scan1<<<512, 256, 0, stream>>>(br, bi, dtm, dtp, spl, A_phase, Sar, Sai, Sbr, Sbi);
    k_scan2<<<8, 256, 0, stream>>>(Sar, Sai, Sbr, Sbi, hinr, hini);
    k_scan3<<<512, 256, 0, stream>>>(br, bi, dtm, dtp, spl, A_phase, hinr, hini, H8);
    k_out_cplx<<<dim3(8, 64), 512, 0, stream>>>(H8, Ppr, Ppi, ssm_s, x_r, x_i, res_s, out);
}

// Round 23
// 336.149 us; speedup vs baseline: 1.1064x; 1.1064x over previous
//
#include <hip/hip_runtime.h>
#include <hip/hip_bf16.h>
#include <hip/hip_fp8.h>
#include <math.h>

// Problem constants
#define BB 4
#define SS 4096
#define DD 1024
#define GG 8
#define NN 64
#define GDIM 128
#define BS (BB*SS)                    // 16384 rows
static const size_t BSD  = (size_t)BS * DD;      // 16,777,216
static const size_t BSGN = (size_t)BS * GG * NN; // 8,388,608

typedef __attribute__((ext_vector_type(8))) short bf16x8;
typedef __attribute__((ext_vector_type(4))) float f32x4;
typedef __attribute__((ext_vector_type(4))) uint u32x4;
typedef unsigned char uchar;

__device__ inline ushort f2b(float x) {
    __hip_bfloat16 h = __float2bfloat16(x);
    return *reinterpret_cast<ushort*>(&h);
}
__device__ inline float b2f(ushort u) {
    union { uint q; float f; } x; x.q = ((uint)u) << 16; return x.f;
}
__device__ inline uchar f2fp8(float x) {
    __hip_fp8_e4m3 h(x);
    return *reinterpret_cast<uchar*>(&h);
}
__device__ inline ushort f2h(float x) {
    _Float16 h = (_Float16)x;
    return *reinterpret_cast<ushort*>(&h);
}
__device__ inline float h2f(ushort u) {
    _Float16 h = *reinterpret_cast<_Float16*>(&u);
    return (float)h;
}
// Exact bf16x8 negation (sign-bit flip on 8 packed bf16).
__device__ __forceinline__ bf16x8 neg8(bf16x8 v) {
    union { bf16x8 b; u32x4 u; } x;
    x.b = v;
    x.u ^= 0x80008000u;
    return x.b;
}

#define GL16(gp, lp) __builtin_amdgcn_global_load_lds( \
    (const __attribute__((address_space(1))) void*)(gp), \
    (__attribute__((address_space(3))) void*)(lp), 16, 0, 0)

// ---------------------------------------------------------------------------
// MFMA GEMM core (m97 structure, r6/r8-proven replay-safe):
// 128x128 tile, 4 waves, BK=32, single LDS buffer, __syncthreads fences.
// A [M][LDA] bf16 row-major (gA pre-offset to tile+lane), B^T [N][LDB].
template<int KD, int LDA, int LDB>
__device__ __forceinline__ void mfma_core(
    const ushort* __restrict__ gA, const ushort* __restrict__ gB,
    ushort* lA, ushort* lB, int wave, int lane, f32x4 (&acc)[4][4])
{
    int r = lane & 15, h = lane >> 4;
    int wm = (wave & 1) * 64, wn = (wave >> 1) * 64;
    ushort* lA0 = lA + wave * 1024;
    ushort* lB0 = lB + wave * 1024;
    for (int k0 = 0; k0 < KD; k0 += 32) {
        __syncthreads();
        GL16(gA + k0,            lA0);
        GL16(gA + k0 + 16*LDA,   lA0 + 512);
        GL16(gB + k0,            lB0);
        GL16(gB + k0 + 16*LDB,   lB0 + 512);
        __syncthreads();
        bf16x8 af[4], bfv[4];
        #pragma unroll
        for (int i = 0; i < 4; i++) af[i]  = *(const bf16x8*)&lA[(wm + i*16 + r)*32 + h*8];
        #pragma unroll
        for (int j = 0; j < 4; j++) bfv[j] = *(const bf16x8*)&lB[(wn + j*16 + r)*32 + h*8];
        #pragma unroll
        for (int i = 0; i < 4; i++)
            #pragma unroll
            for (int j = 0; j < 4; j++)
                acc[i][j] = __builtin_amdgcn_mfma_f32_16x16x32_bf16(af[i], bfv[j], acc[i][j], 0, 0, 0);
    }
}

// ---------------------------------------------------------------------------
// K0: prep.  Wg8 = fp8(Wg*16);  BxT [128][256]; A3 [128][256]; WoP [1024][2048];
// spl = softplus(logA); ctab/stab = cos/sin(theta) expanded to 1024.
__global__ __launch_bounds__(256) void k_prep(
    const float* __restrict__ Wg, const float* __restrict__ BWr, const float* __restrict__ BWi,
    const float* __restrict__ CWr, const float* __restrict__ CWi,
    const float* __restrict__ Wor, const float* __restrict__ Woi,
    const float* __restrict__ logA, const float* __restrict__ theta,
    uchar* __restrict__ Wg8, ushort* __restrict__ BxT, ushort* __restrict__ A3,
    ushort* __restrict__ WoP, float* __restrict__ spl,
    float* __restrict__ ctab, float* __restrict__ stab)
{
    const int S1 = 1048576;           // Wg8
    const int S2 = S1 + 32768;        // BxT
    const int S3 = S2 + 32768;        // A3
    const int S4 = S3 + 2097152;      // WoP
    const int S5 = S4 + 512;          // spl
    const int S6 = S5 + 1024;         // ctab
    const int S7 = S6 + 1024;         // stab
    for (int idx = blockIdx.x * 256 + threadIdx.x; idx < S7; idx += gridDim.x * 256) {
        if (idx < S1) {
            Wg8[idx] = f2fp8(Wg[idx] * 16.0f);   // pow-2 pre-scale, undone in epilogue
        } else if (idx < S2) {
            int j = idx - S1, n = j >> 8, kk = j & 255;
            float v;
            if (n < 64) v = (kk < 128) ? BWr[n*128 + kk] : -BWi[n*128 + (kk-128)];
            else { int n2 = n - 64; v = (kk < 128) ? BWi[n2*128 + kk] : BWr[n2*128 + (kk-128)]; }
            BxT[j] = f2b(v);
        } else if (idx < S3) {
            int j = idx - S2, m = j >> 8, kk = j & 255;
            float v;
            if (m < 64) v = (kk < 128) ? CWr[kk*64 + m] : -CWi[(kk-128)*64 + m];
            else { int n2 = m - 64; v = (kk < 128) ? CWi[kk*64 + n2] : CWr[(kk-128)*64 + n2]; }
            A3[j] = f2b(v);
        } else if (idx < S4) {
            int j = idx - S3, e = j >> 11, c = j & 2047;
            int g = c >> 8, kk = c & 255;
            float v = (kk < 128) ? Wor[(size_t)e*1024 + g*128 + kk]
                                 : Woi[(size_t)e*1024 + g*128 + (kk-128)];
            WoP[j] = f2b(v);
        } else if (idx < S5) {
            int j = idx - S4;
            spl[j] = log1pf(expf(logA[j]));
        } else if (idx < S6) {
            int j = idx - S5;
            ctab[j] = cosf(theta[j >> 3]);
        } else {
            int j = idx - S6;
            stab[j] = sinf(theta[j >> 3]);
        }
    }
}

// ---------------------------------------------------------------------------
// K0b: P = C-combined-with-Wo.  Per g: [Pr;Pi](128x1024) = A3(128x256) @ WoP_g^T.
// Emits separate bf16 Pr/Pi panels [1024 e][512] for the complex-fused out GEMM.
__global__ __launch_bounds__(256) void k_pgemm(
    const ushort* __restrict__ A3, const ushort* __restrict__ WoP,
    ushort* __restrict__ Ppr, ushort* __restrict__ Ppi)
{
    __shared__ ushort lA[4096], lB[4096];
    int g = blockIdx.z;
    int bn = blockIdx.x * 128;
    int tid = threadIdx.x, wave = tid >> 6, lane = tid & 63;
    int row0 = wave*32 + (lane >> 2), col0 = (lane & 3) * 8;
    int r = lane & 15, h = lane >> 4;
    int wm = (wave & 1) * 64, wn = (wave >> 1) * 64;
    f32x4 acc[4][4] = {};
    mfma_core<256, 256, 2048>(A3 + (size_t)row0*256 + col0,
                              WoP + (size_t)(bn + row0)*2048 + g*256 + col0,
                              lA, lB, wave, lane, acc);
    #pragma unroll
    for (int i = 0; i < 4; i++) {
        int mb = wm + i*16 + h*4;
        #pragma unroll
        for (int j = 0; j < 4; j++) {
            int e = bn + wn + j*16 + r;
            #pragma unroll
            for (int t2 = 0; t2 < 4; t2++) {
                int m = mb + t2;
                float v = acc[i][j][t2];
                if (m < 64) {
                    Ppr[(size_t)e*512 + g*64 + m] = f2b(v);
                } else {
                    Ppi[(size_t)e*512 + g*64 + (m - 64)] = f2b(v);
                }
            }
        }
    }
}

// ---------------------------------------------------------------------------
// K1: complex RMSNorm stats: mag (fp8 e4m3) + inv (f32 per row).
__global__ __launch_bounds__(256) void k_norm(
    const float* __restrict__ xr_in, const float* __restrict__ xi_in,
    const float* __restrict__ norm_w,
    uchar* __restrict__ mag_o, float* __restrict__ inv_o)
{
    int row = blockIdx.x;
    int tid = threadIdx.x;
    size_t base = (size_t)row * DD;
    float4 vr = ((const float4*)(xr_in + base))[tid];
    float4 vi = ((const float4*)(xi_in + base))[tid];
    float ss = vr.x*vr.x + vr.y*vr.y + vr.z*vr.z + vr.w*vr.w
             + vi.x*vi.x + vi.y*vi.y + vi.z*vi.z + vi.w*vi.w;
    #pragma unroll
    for (int off = 32; off >= 1; off >>= 1) ss += __shfl_down(ss, off);
    __shared__ float ws4[4];
    if ((tid & 63) == 0) ws4[tid >> 6] = ss;
    __syncthreads();
    float tot = ws4[0] + ws4[1] + ws4[2] + ws4[3];
    float inv = rsqrtf(tot * (1.0f / DD) + 1e-6f);
    float4 w = ((const float4*)norm_w)[tid];
    vr.x *= inv * w.x; vr.y *= inv * w.y; vr.z *= inv * w.z; vr.w *= inv * w.w;
    vi.x *= inv * w.x; vi.y *= inv * w.y; vi.z *= inv * w.z; vi.w *= inv * w.w;
    uchar4 mb;
    mb.x = f2fp8(sqrtf(vr.x*vr.x + vi.x*vi.x + 1e-8f));
    mb.y = f2fp8(sqrtf(vr.y*vr.y + vi.y*vi.y + 1e-8f));
    mb.z = f2fp8(sqrtf(vr.z*vr.z + vi.z*vi.z + 1e-8f));
    mb.w = f2fp8(sqrtf(vr.w*vr.w + vi.w*vi.w + 1e-8f));
    ((uchar4*)(mag_o + base))[tid] = mb;
    if (tid == 0) inv_o[row] = inv;
}

// ---------------------------------------------------------------------------
// K2: gate = sigmoid((mag8 @ Wg8^T)/16 + bg), bf16 out.  WIDE-E fp8 variant
// (r19-proven).  Grid 512 = 8 XCD x 64 chunk (bijective).
__global__ __launch_bounds__(512) void k_gate_fp8(
    const uchar* __restrict__ A8, const uchar* __restrict__ B8,
    const float* __restrict__ bg, ushort* __restrict__ gate)
{
    __shared__ uchar lA[4096], lB[8192];
    int flat = blockIdx.y * 8 + blockIdx.x;          // 0..511
    int nid  = (flat & 7) * 64 + (flat >> 3);        // chunk per XCD
    int bm = (nid >> 2) * 128, bn = (nid & 3) * 256;
    int tid = threadIdx.x, wave = tid >> 6, lane = tid & 63;
    int r = lane & 15, h = lane >> 4;
    int wr = wave >> 2, wc = wave & 3;
    int srow = (lane >> 1);
    int scol = (lane & 1) * 16;
    const uchar* gA = A8 + (size_t)(bm + (wave & 3)*32 + srow)*1024 + scol;       // waves 0-3
    const uchar* gB = B8 + (size_t)(bn + (wave & 3)*64 + srow)*1024 + scol;       // waves 4-7
    uchar* dA = lA + (wave & 3)*1024;
    uchar* dB = lB + (wave & 3)*2048;
    f32x4 acc[4][4] = {};
    for (int k0 = 0; k0 < 1024; k0 += 32) {
        __syncthreads();
        if (wave < 4) {
            GL16(gA + k0, dA);
        } else {
            GL16(gB + k0,            dB);
            GL16(gB + 32*1024 + k0,  dB + 1024);
        }
        __syncthreads();
        long af[4], bfv[4];
        #pragma unroll
        for (int i = 0; i < 4; i++) af[i]  = *(const long*)&lA[(wr*64 + i*16 + r)*32 + h*8];
        #pragma unroll
        for (int j = 0; j < 4; j++) bfv[j] = *(const long*)&lB[(wc*64 + j*16 + r)*32 + h*8];
        #pragma unroll
        for (int i = 0; i < 4; i++)
            #pragma unroll
            for (int j = 0; j < 4; j++)
                acc[i][j] = __builtin_amdgcn_mfma_f32_16x16x32_fp8_fp8(af[i], bfv[j], acc[i][j], 0, 0, 0);
    }
    #pragma unroll
    for (int i = 0; i < 4; i++) {
        int mb = bm + wr*64 + i*16 + h*4;
        #pragma unroll
        for (int j = 0; j < 4; j++) {
            int n = bn + wc*64 + j*16 + r;
            float bias = bg[n];
            #pragma unroll
            for (int t2 = 0; t2 < 4; t2++) {
                float v = acc[i][j][t2] * 0.0625f + bias;   // undo Wg*16
                gate[(size_t)(mb + t2)*DD + n] = f2b(1.0f / (1.0f + __expf(-v)));
            }
        }
    }
}

// ---------------------------------------------------------------------------
// K3: fused rotate + depthwise conv (K=4) + activation + xcat(bf16) + dt.
__global__ __launch_bounds__(256) void k_rotconv(
    const float* __restrict__ xr_raw, const float* __restrict__ xi_raw,
    const float* __restrict__ inv_, const float* __restrict__ norm_w,
    const ushort* __restrict__ gate,
    const float* __restrict__ ctab, const float* __restrict__ stab,
    const float* __restrict__ cw, const float* __restrict__ cb,
    const float* __restrict__ act_thr,
    const float* __restrict__ dtW, const float* __restrict__ dtb,
    ushort* __restrict__ xcat, float* __restrict__ dtm_o, float* __restrict__ dtp_o)
{
    const int CH = 16;
    int row0 = blockIdx.x * CH;
    int s0 = row0 & (SS - 1);
    int t = threadIdx.x, d0 = t * 4;
    int g = d0 >> 7, dd = d0 & 127;
    float4 w4  = *(const float4*)&norm_w[d0];
    float4 ct4 = *(const float4*)&ctab[d0];
    float4 st4 = *(const float4*)&stab[d0];
    float cwv[4][16];
    float cb0[4], cb1[4];
    #pragma unroll
    for (int j = 0; j < 4; j++) {
        #pragma unroll
        for (int q = 0; q < 4; q++)
            *(float4*)&cwv[j][q*4] = *(const float4*)&cw[(size_t)(2*(d0+j))*8 + q*4];
        cb0[j] = cb[2*(d0+j)];
        cb1[j] = cb[2*(d0+j) + 1];
    }
    float4 dtw0a = *(const float4*)&dtW[dd];
    float4 dtw0b = *(const float4*)&dtW[128 + dd];
    float4 dtw1a = *(const float4*)&dtW[256 + dd];
    float4 dtw1b = *(const float4*)&dtW[384 + dd];
    float ea  = __expf(act_thr[0]);
    float db0 = dtb[0], db1 = dtb[1];

    float p1r[4] = {}, p1i[4] = {}, p2r[4] = {}, p2i[4] = {}, p3r[4] = {}, p3i[4] = {};
    auto rotrow = [&](int rr, float (&orr)[4], float (&ori)[4]) {
        float4 a  = *(const float4*)&xr_raw[(size_t)rr*DD + d0];
        float4 bq = *(const float4*)&xi_raw[(size_t)rr*DD + d0];
        ushort4 gq = *(const ushort4*)&gate[(size_t)rr*DD + d0];
        float iv = inv_[rr];
        #pragma unroll
        for (int j = 0; j < 4; j++) {
            float ar = ((const float*)&a)[j]  * iv * ((const float*)&w4)[j];
            float ai = ((const float*)&bq)[j] * iv * ((const float*)&w4)[j];
            float c = ((const float*)&ct4)[j], s = ((const float*)&st4)[j];
            float gg = b2f(((const ushort*)&gq)[j]);
            orr[j] = gg * (ar*c - ai*s);
            ori[j] = gg * (ar*s + ai*c);
        }
    };
    if (s0 >= 1) rotrow(row0 - 1, p1r, p1i);
    if (s0 >= 2) rotrow(row0 - 2, p2r, p2i);
    if (s0 >= 3) rotrow(row0 - 3, p3r, p3i);

    for (int sl = 0; sl < CH; sl++) {
        int row = row0 + sl;
        float rr0[4], ri0[4];
        rotrow(row, rr0, ri0);
        float p0 = 0.f, p1 = 0.f;
        ushort4 ur, ui;
        #pragma unroll
        for (int j = 0; j < 4; j++) {
            float cr = cb0[j]
                + p3r[j]*cwv[j][0]  + p2r[j]*cwv[j][1]  + p1r[j]*cwv[j][2]  + rr0[j]*cwv[j][3]
                + p3i[j]*cwv[j][4]  + p2i[j]*cwv[j][5]  + p1i[j]*cwv[j][6]  + ri0[j]*cwv[j][7];
            float ci = cb1[j]
                + p3r[j]*cwv[j][8]  + p2r[j]*cwv[j][9]  + p1r[j]*cwv[j][10] + rr0[j]*cwv[j][11]
                + p3i[j]*cwv[j][12] + p2i[j]*cwv[j][13] + p1i[j]*cwv[j][14] + ri0[j]*cwv[j][15];
            float act = 1.0f - __expf(-(cr*cr + ci*ci) * ea);
            cr *= act; ci *= act;
            ((ushort*)&ur)[j] = f2b(cr);
            ((ushort*)&ui)[j] = f2b(ci);
            p0 += cr * ((const float*)&dtw0a)[j] + ci * ((const float*)&dtw0b)[j];
            p1 += cr * ((const float*)&dtw1a)[j] + ci * ((const float*)&dtw1b)[j];
        }
        *(ushort4*)&xcat[(size_t)row*2048 + g*256 + dd]       = ur;
        *(ushort4*)&xcat[(size_t)row*2048 + g*256 + 128 + dd] = ui;
        #pragma unroll
        for (int off = 16; off >= 1; off >>= 1) {
            p0 += __shfl_down(p0, off, 32);
            p1 += __shfl_down(p1, off, 32);
        }
        if ((t & 31) == 0) {
            dtm_o[(size_t)row*8 + g] = fminf(fmaxf(__expf(p0 + db0), 1e-4f), 2.0f);
            dtp_o[(size_t)row*8 + g] = fminf(fmaxf(__expf(p1 + db1), 1e-4f), 2.0f);
        }
        #pragma unroll
        for (int j = 0; j < 4; j++) {
            p3r[j] = p2r[j]; p3i[j] = p2i[j];
            p2r[j] = p1r[j]; p2i[j] = p1i[j];
            p1r[j] = rr0[j]; p1i[j] = ri0[j];
        }
    }
}

// ---------------------------------------------------------------------------
// K5: bx = xcat_g @ BxT^T, scaled by dtm; f16 outputs (r19-proven).
__global__ __launch_bounds__(256) void k_bx_mfma(
    const ushort* __restrict__ xcat, const ushort* __restrict__ BxT,
    const float* __restrict__ dtm_,
    ushort* __restrict__ br, ushort* __restrict__ bi)
{
    __shared__ ushort lA[4096], lB[4096];
    int g = blockIdx.z;
    int bm = blockIdx.y * 128;
    int tid = threadIdx.x, wave = tid >> 6, lane = tid & 63;
    int row0 = wave*32 + (lane >> 2), col0 = (lane & 3) * 8;
    int r = lane & 15, h = lane >> 4;
    int wm = (wave & 1) * 64, wn = (wave >> 1) * 64;
    f32x4 acc[4][4] = {};
    mfma_core<256, 2048, 256>(xcat + (size_t)(bm + row0)*2048 + g*256 + col0,
                              BxT + (size_t)row0*256 + col0,
                              lA, lB, wave, lane, acc);
    #pragma unroll
    for (int i = 0; i < 4; i++) {
        int mb = bm + wm + i*16 + h*4;
        #pragma unroll
        for (int j = 0; j < 4; j++) {
            int n = wn + j*16 + r;
            #pragma unroll
            for (int t2 = 0; t2 < 4; t2++) {
                int m = mb + t2;
                float v = acc[i][j][t2] * dtm_[(size_t)m*8 + g];
                if (n < 64) br[(size_t)m*512 + g*64 + n]      = f2h(v);
                else        bi[(size_t)m*512 + g*64 + n - 64] = f2h(v);
            }
        }
    }
}

// ---------------------------------------------------------------------------
// K6: chunked scan, chunk = 64 steps (renorm fires after chunks with c%4==3).
__global__ __launch_bounds__(256) void k_scan1(
    const ushort* __restrict__ br, const ushort* __restrict__ bi,
    const float* __restrict__ dtm_, const float* __restrict__ dtp_,
    const float* __restrict__ spl_t, const float* __restrict__ aph,
    float* __restrict__ Sar, float* __restrict__ Sai,
    float* __restrict__ Sbr, float* __restrict__ Sbi)
{
    int blk = blockIdx.x;                  // 512 = b(4) * c(64) * half(2)
    int half = blk & 1, c = (blk >> 1) & 63, b = blk >> 7;
    int t = half*256 + threadIdx.x;
    int g = t >> 6;
    float spl = spl_t[t], ap = aph[t];
    int row0 = b*SS + c*64;
    size_t idx = (size_t)row0 * 512 + t;
    const float* dtmp = dtm_ + (size_t)row0*8 + g;
    const float* dtpp = dtp_ + (size_t)row0*8 + g;
    float Ar = 1.f, Ai = 0.f, Br = 0.f, Bi = 0.f;
    for (int s0 = 0; s0 < 64; s0 += 4) {
        float vm[4], vp[4], wr[4], wi[4];
        #pragma unroll
        for (int u = 0; u < 4; u++) {
            vm[u] = dtmp[(s0+u)*8]; vp[u] = dtpp[(s0+u)*8];
            wr[u] = h2f(br[idx + (size_t)(s0+u)*512]);
            wi[u] = h2f(bi[idx + (size_t)(s0+u)*512]);
        }
        #pragma unroll
        for (int u = 0; u < 4; u++) {
            float am = __expf(-vm[u]*spl);
            float sa, ca; __sincosf(vp[u]*ap, &sa, &ca);
            float arv = am*ca, aiv = am*sa;
            float nBr = arv*Br - aiv*Bi + wr[u];
            float nBi = arv*Bi + aiv*Br + wi[u];
            float nAr = arv*Ar - aiv*Ai;
            float nAi = arv*Ai + aiv*Ar;
            Br = nBr; Bi = nBi; Ar = nAr; Ai = nAi;
        }
    }
    size_t o = ((size_t)(b*64 + c))*512 + t;
    Sar[o] = Ar; Sai[o] = Ai; Sbr[o] = Br; Sbi[o] = Bi;
}

__global__ __launch_bounds__(256) void k_scan2(
    const float* __restrict__ Sar, const float* __restrict__ Sai,
    const float* __restrict__ Sbr, const float* __restrict__ Sbi,
    float* __restrict__ hinr, float* __restrict__ hini)
{
    int blk = blockIdx.x;                  // 8 = b(4) * half(2)
    int half = blk & 1, b = blk >> 1;
    int t = half*256 + threadIdx.x;
    float hr = 0.f, hi = 0.f;
    for (int c = 0; c < 64; c++) {
        size_t o = ((size_t)(b*64 + c))*512 + t;
        hinr[o] = hr; hini[o] = hi;
        float nr = Sar[o]*hr - Sai[o]*hi + Sbr[o];
        float ni = Sar[o]*hi + Sai[o]*hr + Sbi[o];
        if ((c & 3) == 3) {
            float hn = sqrtf(nr*nr + ni*ni + 1e-8f);
            float sc = fminf(hn, 100.0f) / hn;
            nr *= sc; ni *= sc;
        }
        hr = nr; hi = ni;
    }
}

// scan3: recompute states; write H as bf16 A-matrix [row][1024] = [Hr|Hi].
__global__ __launch_bounds__(256) void k_scan3(
    const ushort* __restrict__ br, const ushort* __restrict__ bi,
    const float* __restrict__ dtm_, const float* __restrict__ dtp_,
    const float* __restrict__ spl_t, const float* __restrict__ aph,
    const float* __restrict__ hinr, const float* __restrict__ hini,
    ushort* __restrict__ Hbf)
{
    int blk = blockIdx.x;
    int half = blk & 1, c = (blk >> 1) & 63, b = blk >> 7;
    int t = half*256 + threadIdx.x;
    int g = t >> 6;
    float spl = spl_t[t], ap = aph[t];
    int row0 = b*SS + c*64;
    size_t idx = (size_t)row0 * 512 + t;
    const float* dtmp = dtm_ + (size_t)row0*8 + g;
    const float* dtpp = dtp_ + (size_t)row0*8 + g;
    size_t o = ((size_t)(b*64 + c))*512 + t;
    float hr = hinr[o], hi = hini[o];
    bool rch = ((c & 3) == 3);
    for (int s0 = 0; s0 < 64; s0 += 4) {
        float vm[4], vp[4], wr[4], wi[4];
        #pragma unroll
        for (int u = 0; u < 4; u++) {
            vm[u] = dtmp[(s0+u)*8]; vp[u] = dtpp[(s0+u)*8];
            wr[u] = h2f(br[idx + (size_t)(s0+u)*512]);
            wi[u] = h2f(bi[idx + (size_t)(s0+u)*512]);
        }
        #pragma unroll
        for (int u = 0; u < 4; u++) {
            float am = __expf(-vm[u]*spl);
            float sa, ca; __sincosf(vp[u]*ap, &sa, &ca);
            float arv = am*ca, aiv = am*sa;
            float nr = arv*hr - aiv*hi + wr[u];
            float ni = arv*hi + aiv*hr + wi[u];
            if (rch && (s0 + u == 63)) {
                float hn = sqrtf(nr*nr + ni*ni + 1e-8f);
                float sc = fminf(hn, 100.0f) / hn;
                nr *= sc; ni *= sc;
            }
            size_t rb = (size_t)(row0 + s0 + u) * 1024;
            Hbf[rb + t]       = f2b(nr);
            Hbf[rb + 512 + t] = f2b(ni);
            hr = nr; hi = ni;
        }
    }
}

// ---------------------------------------------------------------------------
// K7: complex-fused out GEMM, WIDE-E variant (r18/r19/r21 WIN structure).
// Per block 128 m x 256 e, both real+imag; 48KB staged / 512 MFMA per K-step.
// Grid 512 = 8 XCD x 64 chunk (bijective).
__global__ __launch_bounds__(512) void k_out_cplx(
    const ushort* __restrict__ A,      // Hbf [16384][1024] = [Hr(512)|Hi(512)]
    const ushort* __restrict__ Ppr,    // [1024 e][512]
    const ushort* __restrict__ Ppi,    // [1024 e][512]
    const float* __restrict__ ssm,
    const float* __restrict__ xr0, const float* __restrict__ xi0,
    const float* __restrict__ res_scale, float* __restrict__ out)
{
    __shared__ ushort lHr[4096], lHi[4096], lPr[8192], lPi[8192];   // 48KB
    int flat = blockIdx.y * 8 + blockIdx.x;          // 0..511
    int nid  = (flat & 7) * 64 + (flat >> 3);        // chunk per XCD
    int bm = (nid >> 2) * 128, be = (nid & 3) * 256;
    int tid = threadIdx.x, wave = tid >> 6, lane = tid & 63;
    int r = lane & 15, h = lane >> 4;
    int wr = wave >> 2, wc = wave & 3;
    int lrow = lane >> 2;                            // 0..15
    int lcol = (lane & 3) * 8;
    const ushort* gHr = A + (size_t)(bm + wave*16 + lrow)*1024 + lcol;   // +k0 (Hi at +512)
    const ushort* gHi = gHr + 512;
    const ushort* gPr = Ppr + (size_t)(be + wave*32 + lrow)*512 + lcol;  // +q*16*512 +k0
    const ushort* gPi = Ppi + (size_t)(be + wave*32 + lrow)*512 + lcol;
    ushort* dHr = lHr + wave*512;
    ushort* dHi = lHi + wave*512;
    ushort* dPr = lPr + wave*1024;
    ushort* dPi = lPi + wave*1024;
    f32x4 accr[4][4] = {};
    f32x4 acci[4][4] = {};
    for (int k0 = 0; k0 < 512; k0 += 32) {
        __syncthreads();
        GL16(gHr + k0, dHr);
        GL16(gHi + k0, dHi);
        GL16(gPr + k0,          dPr);
        GL16(gPr + 16*512 + k0, dPr + 512);
        GL16(gPi + k0,          dPi);
        GL16(gPi + 16*512 + k0, dPi + 512);
        __syncthreads();
        bf16x8 hrf[4], hif[4], prf[4], pif[4], npif[4];
        #pragma unroll
        for (int i = 0; i < 4; i++) {
            int ro = (wr*64 + i*16 + r)*32 + h*8;
            hrf[i] = *(const bf16x8*)&lHr[ro];
            hif[i] = *(const bf16x8*)&lHi[ro];
        }
        #pragma unroll
        for (int j = 0; j < 4; j++) {
            int ro = (wc*64 + j*16 + r)*32 + h*8;
            prf[j] = *(const bf16x8*)&lPr[ro];
            pif[j] = *(const bf16x8*)&lPi[ro];
            npif[j] = neg8(pif[j]);
        }
        #pragma unroll
        for (int i = 0; i < 4; i++)
            #pragma unroll
            for (int j = 0; j < 4; j++) {
                accr[i][j] = __builtin_amdgcn_mfma_f32_16x16x32_bf16(hrf[i], prf[j],  accr[i][j], 0, 0, 0);
                accr[i][j] = __builtin_amdgcn_mfma_f32_16x16x32_bf16(hif[i], npif[j], accr[i][j], 0, 0, 0);
                acci[i][j] = __builtin_amdgcn_mfma_f32_16x16x32_bf16(hrf[i], pif[j],  acci[i][j], 0, 0, 0);
                acci[i][j] = __builtin_amdgcn_mfma_f32_16x16x32_bf16(hif[i], prf[j],  acci[i][j], 0, 0, 0);
            }
    }
    float rs = res_scale[0];
    #pragma unroll
    for (int i = 0; i < 4; i++) {
        int mb = bm + wr*64 + i*16 + h*4;
        #pragma unroll
        for (int j = 0; j < 4; j++) {
            int e = be + wc*64 + j*16 + r;
            float sc = ssm[e] * rs;
            #pragma unroll
            for (int t2 = 0; t2 < 4; t2++) {
                size_t p = (size_t)(mb + t2)*DD + e;
                float2 v;
                v.x = xr0[p] + accr[i][j][t2]*sc;
                v.y = xi0[p] + acci[i][j][t2]*sc;
                *(float2*)&out[2*p] = v;
            }
        }
    }
}

// ---------------------------------------------------------------------------
extern "C" void kernel_launch(void* const* d_in, const int* in_sizes, int n_in,
                              void* d_out, int out_size, void* d_ws, size_t ws_size,
                              hipStream_t stream) {
    const float* x_r      = (const float*)d_in[0];
    const float* x_i      = (const float*)d_in[1];
    const float* norm_w   = (const float*)d_in[2];
    const float* sg_theta = (const float*)d_in[3];
    const float* sg_Wg    = (const float*)d_in[4];
    const float* sg_bg    = (const float*)d_in[5];
    const float* conv_w   = (const float*)d_in[6];
    const float* conv_b   = (const float*)d_in[7];
    const float* log_A    = (const float*)d_in[8];
    const float* A_phase  = (const float*)d_in[9];
    const float* B_Wr     = (const float*)d_in[10];
    const float* B_Wi     = (const float*)d_in[11];
    const float* C_Wr     = (const float*)d_in[12];
    const float* C_Wi     = (const float*)d_in[13];
    const float* dt_W     = (const float*)d_in[14];
    const float* dt_b     = (const float*)d_in[15];
    const float* out_Wr   = (const float*)d_in[16];
    const float* out_Wi   = (const float*)d_in[17];
    const float* act_thr  = (const float*)d_in[18];
    const float* ssm_s    = (const float*)d_in[19];
    const float* res_s    = (const float*)d_in[20];
    float* out = (float*)d_out;
    float* ws  = (float*)d_ws;

    ushort* gate  = (ushort*)ws;                         // BS*1024 bf16 (in BSD f32 slots)
    ushort* xcat  = (ushort*)(ws + BSD);                 // BS*2048 bf16 (BSD f32 slots)
    uchar*  mag8  = (uchar*)(ws + 2*BSD);                // BS*1024 fp8 (16MB, in BSGN slot)
    ushort* br    = (ushort*)(ws + 2*BSD + BSGN);        // BSGN f16 (in BSGN f32 slots)
    ushort* bi    = (ushort*)(ws + 2*BSD + 2*BSGN);      // BSGN f16
    ushort* Hbf   = (ushort*)(ws + 2*BSD + 3*BSGN);      // BS*1024 bf16 (BSGN f32 slots)
    float*  sm    = ws + 2*BSD + 4*BSGN;
    float*  dtm   = sm;
    float*  dtp   = sm + 131072;
    float*  Sar   = sm + 2*131072;
    float*  Sai   = sm + 3*131072;
    float*  Sbr   = sm + 4*131072;
    float*  Sbi   = sm + 5*131072;
    float*  hinr  = sm + 6*131072;
    float*  hini  = sm + 7*131072;
    float*  inv   = sm + 8*131072;                       // 16384
    float*  spl   = inv + 16384;                         // 512
    float*  ctab  = spl + 512;                           // 1024
    float*  stab  = ctab + 1024;                         // 1024
    uchar*  Wg8   = (uchar*)(stab + 1024);               // 1048576 bytes (262144 f32 slots)
    ushort* BxT   = (ushort*)(stab + 1024 + 262144);     // 32768 ushorts
    ushort* A3    = BxT + 32768;                         // 32768
    ushort* WoP   = A3 + 32768;                          // 2097152
    ushort* Ppr   = WoP + 2097152;                       // 524288
    ushort* Ppi   = Ppr + 524288;                        // 524288

    k_prep<<<2048, 256, 0, stream>>>(sg_Wg, B_Wr, B_Wi, C_Wr, C_Wi, out_Wr, out_Wi,
                                     log_A, sg_theta, Wg8, BxT, A3, WoP, spl, ctab, stab);
    k_pgemm<<<dim3(8, 1, 8), 256, 0, stream>>>(A3, WoP, Ppr, Ppi);
    k_norm<<<BS, 256, 0, stream>>>(x_r, x_i, norm_w, mag8, inv);
    k_gate_fp8<<<dim3(8, 64), 512, 0, stream>>>(mag8, Wg8, sg_bg, gate);
    k_rotconv<<<BS/16, 256, 0, stream>>>(x_r, x_i, inv, norm_w, gate, ctab, stab,
                                         conv_w, conv_b, act_thr, dt_W, dt_b,
                                         xcat, dtm, dtp);
    k_bx_mfma<<<dim3(1, 128, 8), 256, 0, stream>>>(xcat, BxT, dtm, br, bi);
    k_scan1<<<512, 256, 0, stream>>>(br, bi, dtm, dtp, spl, A_phase, Sar, Sai, Sbr, Sbi);
    k_scan2<<<8, 256, 0, stream>>>(Sar, Sai, Sbr, Sbi, hinr, hini);
    k_scan3<<<512, 256, 0, stream>>>(br, bi, dtm, dtp, spl, A_phase, hinr, hini, Hbf);
    k_out_cplx<<<dim3(8, 64), 512, 0, stream>>>(Hbf, Ppr, Ppi, ssm_s, x_r, x_i, res_s, out);
}